// Round 11
// baseline (267.974 us; speedup 1.0000x reference)
//
#include <hip/hip_runtime.h>
#include <hip/hip_bf16.h>
#include <math.h>

static constexpr int kN   = 50000;   // nodes
static constexpr int kE   = 800000;  // edges
static constexpr int kHID = 256;
static constexpr int kHD  = 32;

typedef short bf16x8 __attribute__((ext_vector_type(8)));
typedef float f32x4  __attribute__((ext_vector_type(4)));
typedef float f32x2  __attribute__((ext_vector_type(2)));
typedef unsigned short us8 __attribute__((ext_vector_type(8)));
typedef unsigned int u32x4 __attribute__((ext_vector_type(4)));
typedef int i32x2 __attribute__((ext_vector_type(2)));
typedef int i32x4 __attribute__((ext_vector_type(4)));

__device__ __forceinline__ float b2f(unsigned short u) {
  union { unsigned v; float f; } c; c.v = ((unsigned)u) << 16; return c.f;
}

__device__ __forceinline__ unsigned short f2bu(float f) {
  __hip_bfloat16 b = __float2bfloat16(f);
  union { __hip_bfloat16 b; unsigned short u; } c; c.b = b; return c.u;
}

// unpack u32 holding 2 bf16 (channels 2j, 2j+1) into f32x2
__device__ __forceinline__ f32x2 bf2up(unsigned u) {
  union { unsigned v; float f; } lo, hi;
  lo.v = u << 16; hi.v = u & 0xffff0000u;
  return f32x2{lo.f, hi.f};
}

// quad-local butterfly add via DPP (no LDS round-trip).
__device__ __forceinline__ float quad_add_xor1(float s) {
  union { float f; int i; } a, b;
  a.f = s;
  b.i = __builtin_amdgcn_mov_dpp(a.i, 0xB1, 0xF, 0xF, true);  // quad_perm [1,0,3,2]
  return s + b.f;
}
__device__ __forceinline__ float quad_add_xor2(float s) {
  union { float f; int i; } a, b;
  a.f = s;
  b.i = __builtin_amdgcn_mov_dpp(a.i, 0x4E, 0xF, 0xF, true);  // quad_perm [2,3,0,1]
  return s + b.f;
}

// global -> LDS async copy, 16 B per lane; LDS dest = uniform base + lane*16
__device__ __forceinline__ void load_lds16(const void* g, void* l) {
  __builtin_amdgcn_global_load_lds(
      (const __attribute__((address_space(1))) unsigned int*)(unsigned long long)(uintptr_t)g,
      (__attribute__((address_space(3))) unsigned int*)(unsigned int)(uintptr_t)l,
      16, 0, 0);
}

// ---------------------------------------------------------------------------
// Merged prep: one launch.
//  blocks [0, 6250)        : h -> bf16 (8 elems/thread, 16B stores)
//  blocks [6250, 7018)     : build Bt[768][256] + biasP[768]
//  blocks [7018, 7214)     : row_ptr lower_bound
//  blocks [7214, 7996)     : pack (col_ind, val) int2 cv[]
// ---------------------------------------------------------------------------
__global__ void prep_all_kernel(
    const float* __restrict__ h, __hip_bfloat16* __restrict__ Ah,
    const float* __restrict__ Wq, const float* __restrict__ bq,
    const float* __restrict__ Wk, const float* __restrict__ bk,
    const float* __restrict__ Wv, const float* __restrict__ bv,
    __hip_bfloat16* __restrict__ Bt, float* __restrict__ biasP,
    const int* __restrict__ er, int* __restrict__ rp,
    const int* __restrict__ ci, const float* __restrict__ vl,
    i32x2* __restrict__ cv) {
  int b = blockIdx.x;
  if (b < 6250) {                      // ---- split_h ----
    int idx = b * 256 + threadIdx.x;
    const f32x4* hp = (const f32x4*)(h + (size_t)idx * 8);
    f32x4 a = hp[0], c = hp[1];
    us8 o;
    o[0] = f2bu(a[0]); o[1] = f2bu(a[1]); o[2] = f2bu(a[2]); o[3] = f2bu(a[3]);
    o[4] = f2bu(c[0]); o[5] = f2bu(c[1]); o[6] = f2bu(c[2]); o[7] = f2bu(c[3]);
    *(us8*)(Ah + (size_t)idx * 8) = o;
    return;
  }
  b -= 6250;
  if (b < 768) {                       // ---- build_bt ----
    const int n  = b;
    const int kk = threadIdx.x;
    const int g  = n >> 8;
    const int cc = n & 255;
    const int c  = ((cc & 31) << 3) + (cc >> 5);
    const float scale = (g == 0) ? 0.17677669529663689f : 1.0f;
    const float* W = (g == 0) ? Wq : ((g == 1) ? Wk : Wv);
    Bt[n * 256 + kk] = __float2bfloat16(W[kk * 256 + c] * scale);
    if (kk == 0) {
      const float* bb = (g == 0) ? bq : ((g == 1) ? bk : bv);
      biasP[n] = bb[c] * scale;
    }
    return;
  }
  b -= 768;
  if (b < 196) {                       // ---- row_ptr ----
    int i = b * 256 + threadIdx.x;
    if (i > kN) return;
    int lo = 0, hi = kE;
    while (lo < hi) {
      int mid = (lo + hi) >> 1;
      if (er[mid] < i) lo = mid + 1; else hi = mid;
    }
    rp[i] = lo;
    return;
  }
  b -= 196;
  {                                    // ---- cv pack ----
    const int e4 = (b * 256 + threadIdx.x) * 4;
    if (e4 < kE) {
      i32x4 c = *(const i32x4*)(ci + e4);
      f32x4 w = *(const f32x4*)(vl + e4);
      i32x4 o0 = {c[0], __float_as_int(w[0]), c[1], __float_as_int(w[1])};
      i32x4 o1 = {c[2], __float_as_int(w[2]), c[3], __float_as_int(w[3])};
      *(i32x4*)(cv + e4)     = o0;
      *(i32x4*)(cv + e4 + 2) = o1;
    }
  }
}

// ---------------------------------------------------------------------------
// Fused MFMA GEMM (v8, unchanged): C[50000][768] = A * Bt^T + bias.
// 64 KB LDS double-buffer, prefetch next K-tile before computing current,
// one barrier per K-step. XCD-aware decode; LDS-staged coalesced epilogue.
// ---------------------------------------------------------------------------
__global__ __launch_bounds__(256) void gemm_qkv_kernel(
    const __hip_bfloat16* __restrict__ Ah,
    const __hip_bfloat16* __restrict__ Bt, const float* __restrict__ biasP,
    __hip_bfloat16* __restrict__ qb, __hip_bfloat16* __restrict__ kvb) {
  __shared__ __align__(16) char smemRaw[65536];   // A0|B0|A1|B1 x 16 KB
  short* smemC = (short*)smemRaw;                 // [128][136] C tile (epilogue)

  // XCD-aware decode: L = xcd + 8*(n + 6*mg), m-tile = mg*8 + xcd
  const int L   = blockIdx.x;
  const int xcd = L & 7;
  const int t_  = L >> 3;
  const int nt  = t_ % 6;
  const int mg  = t_ / 6;
  const int mt  = mg * 8 + xcd;
  if (mt >= 391) return;
  const int colBase = nt * 128;
  const int rowBase = mt * 128;

  const int tid  = threadIdx.x;
  const int wave = tid >> 6;
  const int lane = tid & 63;
  const int wm = wave & 1;            // M half of tile
  const int wn = wave >> 1;           // N half

  f32x4 acc[4][4];
#pragma unroll
  for (int i = 0; i < 4; ++i)
#pragma unroll
    for (int j = 0; j < 4; ++j) acc[i][j] = f32x4{0.f, 0.f, 0.f, 0.f};

  // stage A+B tiles for K-step base K0 into buffer BUF (async, no wait)
#define STAGE(BUF, K0)                                                      \
  {                                                                         \
    char* dA = smemRaw + (BUF) * 32768;                                     \
    char* dB = dA + 16384;                                                  \
    _Pragma("unroll")                                                       \
    for (int j = 0; j < 4; ++j) {                                           \
      int s = (wave * 4 + j) * 64 + lane;                                   \
      int r = s >> 3, cp = s & 7;                                           \
      int c = cp ^ (r & 7);                                                 \
      int grow = rowBase + r;                                               \
      grow = grow < kN ? grow : kN - 1;                                     \
      load_lds16((const char*)Ah + (size_t)grow * 512 + (K0) * 2 + c * 16,  \
                 dA + (wave * 4 + j) * 1024);                               \
      load_lds16((const char*)Bt + (size_t)(colBase + r) * 512 + (K0) * 2 + c * 16, \
                 dB + (wave * 4 + j) * 1024);                               \
    }                                                                       \
  }

  STAGE(0, 0);
  __syncthreads();                     // tile 0 resident

  const int rq = lane & 15, qd = lane >> 4;
#pragma unroll
  for (int t = 0; t < 4; ++t) {
    if (t < 3) STAGE((t + 1) & 1, (t + 1) * 64);   // prefetch next tile
    const short* sA = (const short*)(smemRaw + (t & 1) * 32768);
    const short* sB = sA + 8192;                    // +16384 bytes
#pragma unroll
    for (int ks = 0; ks < 2; ++ks) {
      bf16x8 af[4], bfr[4];
#pragma unroll
      for (int mi = 0; mi < 4; ++mi) {
        int r = wm * 64 + mi * 16 + rq;
        int c = (ks * 4 + qd) ^ (r & 7);
        af[mi] = *(const bf16x8*)&sA[r * 64 + c * 8];
      }
#pragma unroll
      for (int nj = 0; nj < 4; ++nj) {
        int r = wn * 64 + nj * 16 + rq;
        int c = (ks * 4 + qd) ^ (r & 7);
        bfr[nj] = *(const bf16x8*)&sB[r * 64 + c * 8];
      }
#pragma unroll
      for (int mi = 0; mi < 4; ++mi)
#pragma unroll
        for (int nj = 0; nj < 4; ++nj)
          acc[mi][nj] = __builtin_amdgcn_mfma_f32_16x16x32_bf16(
              af[mi], bfr[nj], acc[mi][nj], 0, 0, 0);
    }
    __syncthreads();   // drains prefetch (vmcnt) AFTER compute; next tile ready
  }
#undef STAGE

  // ---- epilogue: stage bf16 C tile in LDS, then coalesced stores.
  // C frag layout: row=(lane>>4)*4+reg, col=lane&15 (verified m89/m91).
#pragma unroll
  for (int nj = 0; nj < 4; ++nj) {
    const int cl = wn * 64 + nj * 16 + (lane & 15);
    const float bb = biasP[colBase + cl];
#pragma unroll
    for (int mi = 0; mi < 4; ++mi) {
      const int rl = wm * 64 + mi * 16 + (lane >> 4) * 4;
#pragma unroll
      for (int reg = 0; reg < 4; ++reg) {
        smemC[(rl + reg) * 136 + cl] = (short)f2bu(acc[mi][nj][reg] + bb);
      }
    }
  }
  __syncthreads();

  const int g = colBase >> 8;   // block-uniform: 0=q 1=k 2=v
#pragma unroll
  for (int it = 0; it < 8; ++it) {
    const int r   = it * 16 + (tid >> 4);      // 0..127
    const int c16 = tid & 15;                  // 16B chunk within row
    const int row = rowBase + r;
    if (row < kN) {
      bf16x8 vls = *(const bf16x8*)&smemC[r * 136 + c16 * 8];
      const int cc = (colBase & 255) + c16 * 8;
      __hip_bfloat16* dst =
          (g == 0) ? (qb + (size_t)row * 256 + cc)
                   : (kvb + (size_t)row * 512 + (g == 2 ? 256 : 0) + cc);
      *(bf16x8*)dst = vls;
    }
  }
}

// ---------------------------------------------------------------------------
// Fused SDDMM + segment softmax + SpMM (v10).
//
// v10 = v6 loop + TWO CONSECUTIVE ROWS PER WAVE with cross-row warmup
// overlap (the concurrency disambiguator):
//   - row r1's group-0 (col,val) loaded in the PROLOGUE (covered by all of
//     row r0's processing);
//   - row r1's group-0 k/v gathers issued BEFORE r0's epilogue (addresses
//     resident; epilogue covers the issue);
//   - removes the row_ptr->cv->gather startup chain for half of all rows.
// Row loop itself is exact v6 (best measured: unconditional refills,
// stride-8 tail, packed cv dwordx2, f32x2 math, DPP quad reduce, exp2).
// ---------------------------------------------------------------------------
__global__ __launch_bounds__(128) void edge_attn_kernel(
    const __hip_bfloat16* __restrict__ qb, const __hip_bfloat16* __restrict__ kvb,
    const int* __restrict__ row_ptr, const i32x2* __restrict__ cvp,
    float* __restrict__ out) {
  const int wave = threadIdx.x >> 6;
  const int lane = threadIdx.x & 63;
  const int half = lane >> 5;        // which edge of the pair
  const int sl   = lane & 31;        // channel-group lane (8 ch each)
  const int r0 = blockIdx.x * 4 + wave * 2;   // this wave: rows r0, r0+1
  if (r0 >= kN) return;
  const int r1 = r0 + 1;
  const bool haveR1 = (r1 < kN);

  const char* kvbL = (const char*)kvb + sl * 16;

  // ---- prologue: row bounds (consecutive CSR), q(r0), g0 cols both rows
  const int e00 = row_ptr[r0];
  const int e01 = row_ptr[r0 + 1];
  const int eB1 = haveR1 ? row_ptr[r0 + 2] : e01;

  const us8 qu0 = *(const us8*)(qb + (size_t)r0 * 256 + sl * 8);

  u32x4 kS[4], vS[4]; float wS[4];
  i32x2 cvA[4], cvB[4];
  i32x2 c0N[4];                        // row r1 group-0 cols (prefetched)

  if (haveR1 && e01 < eB1) {
    const int elB = eB1 - 1;
#pragma unroll
    for (int j = 0; j < 4; ++j) c0N[j] = cvp[min(e01 + 2 * j + half, elB)];
  }

  if (e00 < e01) {                     // row r0 warmup
    const int elA = e01 - 1;
    i32x2 c0[4];
#pragma unroll
    for (int j = 0; j < 4; ++j) c0[j] = cvp[min(e00 + 2 * j + half, elA)];
#pragma unroll
    for (int j = 0; j < 4; ++j) cvA[j] = cvp[min(e00 + 8 + 2 * j + half, elA)];
#pragma unroll
    for (int j = 0; j < 4; ++j) cvB[j] = cvp[min(e00 + 16 + 2 * j + half, elA)];
#pragma unroll
    for (int j = 0; j < 4; ++j) {
      const size_t off = (size_t)c0[j][0] * 1024;
      kS[j] = *(const u32x4*)(kvbL + off);
      vS[j] = *(const u32x4*)(kvbL + off + 512);
      wS[j] = __int_as_float(c0[j][1]);
    }
  }

  float qf2a[8];                       // qf2 as flat floats (pairs)
#pragma unroll
  for (int j = 0; j < 8; ++j) qf2a[j] = b2f(qu0[j]) * 1.4426950408889634f;

  float denom = 0.f;
  f32x2 acc2[4];
#pragma unroll
  for (int j = 0; j < 4; ++j) acc2[j] = f32x2{0.f, 0.f};

  int e0, e1, elast;                   // current-row loop bounds

  // v6 group: consume [EB,EB+8); refill k/v for [EB+8,EB+16) from CB;
  // reload CB with cols for [EB+24,EB+32) (clamped; junk at tail is
  // overwritten by the cross-row bridge or never consumed).
#define ATTN_GROUP(EB, CB)                                                \
    _Pragma("unroll")                                                     \
    for (int j = 0; j < 4; ++j) {                                         \
      const u32x4 kc = kS[j], vc = vS[j];                                 \
      const float wc = wS[j];                                             \
      {                                                                   \
        const size_t off = (size_t)CB[j][0] * 1024;                       \
        kS[j] = *(const u32x4*)(kvbL + off);                              \
        vS[j] = *(const u32x4*)(kvbL + off + 512);                        \
        wS[j] = __int_as_float(CB[j][1]);                                 \
      }                                                                   \
      {                                                                   \
        const int en = min((EB) + 24 + 2 * j + half, elast);              \
        CB[j] = cvp[en];                                                  \
      }                                                                   \
      f32x2 s2 = f32x2{qf2a[0], qf2a[1]} * bf2up(kc[0]);                  \
      s2 += f32x2{qf2a[2], qf2a[3]} * bf2up(kc[1]);                       \
      s2 += f32x2{qf2a[4], qf2a[5]} * bf2up(kc[2]);                       \
      s2 += f32x2{qf2a[6], qf2a[7]} * bf2up(kc[3]);                       \
      float s = s2[0] + s2[1];                                            \
      s = quad_add_xor1(s);                                               \
      s = quad_add_xor2(s);        /* 4-lane head group reduced */        \
      s *= wc;                                                            \
      float p = exp2f(s);                                                 \
      p = (((EB) + 2 * j + half) < e1) ? p : 0.f;                         \
      denom += p;                                                         \
      const f32x2 p2 = {p, p};                                            \
      acc2[0] += p2 * bf2up(vc[0]);                                       \
      acc2[1] += p2 * bf2up(vc[1]);                                       \
      acc2[2] += p2 * bf2up(vc[2]);                                       \
      acc2[3] += p2 * bf2up(vc[3]);                                       \
    }

#define ROW_LOOP                                                          \
    {                                                                     \
      int e = e0;                                                         \
      for (;;) {                                                          \
        ATTN_GROUP(e, cvA);                                               \
        e += 8; if (e >= e1) break;                                       \
        ATTN_GROUP(e, cvB);                                               \
        e += 8; if (e >= e1) break;                                       \
      }                                                                   \
    }

  // epilogue: combine halves, normalize, store row R.
#define ROW_EPILOGUE(R)                                                   \
    {                                                                     \
      float accs[8];                                                      \
      _Pragma("unroll")                                                   \
      for (int j = 0; j < 8; ++j) {                                       \
        float a = (j & 1) ? acc2[j >> 1][1] : acc2[j >> 1][0];            \
        accs[j] = a + __shfl_xor(a, 32);                                  \
      }                                                                   \
      float dn = denom + __shfl_xor(denom, 32);                           \
      const float inv = (dn > 0.f) ? (1.0f / dn) : 0.f;                   \
      const int hh = sl >> 2;                                             \
      const int dbase = (sl & 3) * 8 + half * 4;                          \
      float* o = out + (size_t)(R) * 256 + hh;                            \
      _Pragma("unroll")                                                   \
      for (int jj = 0; jj < 4; ++jj)                                      \
        o[(dbase + jj) * 8] = accs[half * 4 + jj] * inv;                  \
    }

  // ---- row r0 ----
  if (e00 < e01) {
    e0 = e00; e1 = e01; elast = e01 - 1;
    ROW_LOOP;
  }

  // ---- cross-row bridge: issue r1's g0 k/v gathers + next cv banks + q
  // BEFORE r0's epilogue (kS/vS free; addresses were prefetched).
  us8 qu1;
  if (haveR1) {
    qu1 = *(const us8*)(qb + (size_t)r1 * 256 + sl * 8);
    if (e01 < eB1) {
      const int elB = eB1 - 1;
#pragma unroll
      for (int j = 0; j < 4; ++j) {
        const size_t off = (size_t)c0N[j][0] * 1024;
        kS[j] = *(const u32x4*)(kvbL + off);
        vS[j] = *(const u32x4*)(kvbL + off + 512);
        wS[j] = __int_as_float(c0N[j][1]);
      }
#pragma unroll
      for (int j = 0; j < 4; ++j) cvA[j] = cvp[min(e01 + 8 + 2 * j + half, elB)];
#pragma unroll
      for (int j = 0; j < 4; ++j) cvB[j] = cvp[min(e01 + 16 + 2 * j + half, elB)];
    }
  }

  ROW_EPILOGUE(r0);

  // ---- row r1 ----
  if (haveR1) {
#pragma unroll
    for (int j = 0; j < 8; ++j) qf2a[j] = b2f(qu1[j]) * 1.4426950408889634f;
    denom = 0.f;
#pragma unroll
    for (int j = 0; j < 4; ++j) acc2[j] = f32x2{0.f, 0.f};
    if (e01 < eB1) {
      e0 = e01; e1 = eB1; elast = eB1 - 1;
      ROW_LOOP;
    }
    ROW_EPILOGUE(r1);
  }
#undef ATTN_GROUP
#undef ROW_LOOP
#undef ROW_EPILOGUE
}

// ---------------------------------------------------------------------------
extern "C" void kernel_launch(void* const* d_in, const int* in_sizes, int n_in,
                              void* d_out, int out_size, void* d_ws, size_t ws_size,
                              hipStream_t stream) {
  const float* h   = (const float*)d_in[0];
  const float* val = (const float*)d_in[1];
  const float* Wq  = (const float*)d_in[2];
  const float* bq  = (const float*)d_in[3];
  const float* Wk  = (const float*)d_in[4];
  const float* bk  = (const float*)d_in[5];
  const float* Wv  = (const float*)d_in[6];
  const float* bv  = (const float*)d_in[7];
  const int* edge_rows = (const int*)d_in[8];
  const int* col_ind   = (const int*)d_in[9];
  float* out = (float*)d_out;

  char* ws = (char*)d_ws;
  __hip_bfloat16* Ah  = (__hip_bfloat16*)ws;                 ws += (size_t)kN * 256 * 2;
  __hip_bfloat16* Bt  = (__hip_bfloat16*)ws;                 ws += (size_t)768 * 256 * 2;
  float*          biasP = (float*)ws;                        ws += 768 * 4;
  __hip_bfloat16* qb  = (__hip_bfloat16*)ws;                 ws += (size_t)kN * 256 * 2;
  __hip_bfloat16* kvb = (__hip_bfloat16*)ws;                 ws += (size_t)kN * 512 * 2;
  int* row_ptr = (int*)ws;                                   ws += ((size_t)(kN + 1) * 4 + 127) & ~127ull;
  i32x2* cv = (i32x2*)ws;

  // merged prep: split_h + build_bt + row_ptr + cv pack in ONE launch
  prep_all_kernel<<<6250 + 768 + 196 + 782, 256, 0, stream>>>(
      h, Ah, Wq, bq, Wk, bk, Wv, bv, Bt, biasP,
      edge_rows, row_ptr, col_ind, val, cv);

  // 391 M-tiles padded to 49 groups of 8; 6 N-tiles; 8 XCD slots
  gemm_qkv_kernel<<<8 * 6 * 49, 256, 0, stream>>>(Ah, Bt, biasP, qb, kvb);

  // 4 rows per block (2 waves x 2 rows)
  edge_attn_kernel<<<(kN + 3) / 4, 128, 0, stream>>>(qb, kvb, row_ptr, cv, out);
}

// Round 12
// 264.835 us; speedup vs baseline: 1.0119x; 1.0119x over previous
//
#include <hip/hip_runtime.h>
#include <hip/hip_bf16.h>
#include <math.h>

static constexpr int kN   = 50000;   // nodes
static constexpr int kE   = 800000;  // edges
static constexpr int kHID = 256;
static constexpr int kHD  = 32;

typedef short bf16x8 __attribute__((ext_vector_type(8)));
typedef float f32x4  __attribute__((ext_vector_type(4)));
typedef float f32x2  __attribute__((ext_vector_type(2)));
typedef unsigned short us8 __attribute__((ext_vector_type(8)));
typedef unsigned int u32x4 __attribute__((ext_vector_type(4)));
typedef int i32x2 __attribute__((ext_vector_type(2)));
typedef int i32x4 __attribute__((ext_vector_type(4)));

__device__ __forceinline__ float b2f(unsigned short u) {
  union { unsigned v; float f; } c; c.v = ((unsigned)u) << 16; return c.f;
}

__device__ __forceinline__ unsigned short f2bu(float f) {
  __hip_bfloat16 b = __float2bfloat16(f);
  union { __hip_bfloat16 b; unsigned short u; } c; c.b = b; return c.u;
}

// unpack u32 holding 2 bf16 (channels 2j, 2j+1) into f32x2
__device__ __forceinline__ f32x2 bf2up(unsigned u) {
  union { unsigned v; float f; } lo, hi;
  lo.v = u << 16; hi.v = u & 0xffff0000u;
  return f32x2{lo.f, hi.f};
}

// quad-local butterfly add via DPP (no LDS round-trip).
__device__ __forceinline__ float quad_add_xor1(float s) {
  union { float f; int i; } a, b;
  a.f = s;
  b.i = __builtin_amdgcn_mov_dpp(a.i, 0xB1, 0xF, 0xF, true);  // quad_perm [1,0,3,2]
  return s + b.f;
}
__device__ __forceinline__ float quad_add_xor2(float s) {
  union { float f; int i; } a, b;
  a.f = s;
  b.i = __builtin_amdgcn_mov_dpp(a.i, 0x4E, 0xF, 0xF, true);  // quad_perm [2,3,0,1]
  return s + b.f;
}

// global -> LDS async copy, 16 B per lane; LDS dest = uniform base + lane*16
__device__ __forceinline__ void load_lds16(const void* g, void* l) {
  __builtin_amdgcn_global_load_lds(
      (const __attribute__((address_space(1))) unsigned int*)(unsigned long long)(uintptr_t)g,
      (__attribute__((address_space(3))) unsigned int*)(unsigned int)(uintptr_t)l,
      16, 0, 0);
}

// ---------------------------------------------------------------------------
// Merged prep: one launch.
//  blocks [0, 6250)        : h -> bf16 (8 elems/thread, 16B stores)
//  blocks [6250, 7018)     : build Bt[768][256] + biasP[768]
//  blocks [7018, 7214)     : row_ptr lower_bound
//  blocks [7214, 7996)     : pack (col_ind, val) int2 cv[]
// ---------------------------------------------------------------------------
__global__ void prep_all_kernel(
    const float* __restrict__ h, __hip_bfloat16* __restrict__ Ah,
    const float* __restrict__ Wq, const float* __restrict__ bq,
    const float* __restrict__ Wk, const float* __restrict__ bk,
    const float* __restrict__ Wv, const float* __restrict__ bv,
    __hip_bfloat16* __restrict__ Bt, float* __restrict__ biasP,
    const int* __restrict__ er, int* __restrict__ rp,
    const int* __restrict__ ci, const float* __restrict__ vl,
    i32x2* __restrict__ cv) {
  int b = blockIdx.x;
  if (b < 6250) {                      // ---- split_h ----
    int idx = b * 256 + threadIdx.x;
    const f32x4* hp = (const f32x4*)(h + (size_t)idx * 8);
    f32x4 a = hp[0], c = hp[1];
    us8 o;
    o[0] = f2bu(a[0]); o[1] = f2bu(a[1]); o[2] = f2bu(a[2]); o[3] = f2bu(a[3]);
    o[4] = f2bu(c[0]); o[5] = f2bu(c[1]); o[6] = f2bu(c[2]); o[7] = f2bu(c[3]);
    *(us8*)(Ah + (size_t)idx * 8) = o;
    return;
  }
  b -= 6250;
  if (b < 768) {                       // ---- build_bt ----
    const int n  = b;
    const int kk = threadIdx.x;
    const int g  = n >> 8;
    const int cc = n & 255;
    const int c  = ((cc & 31) << 3) + (cc >> 5);
    const float scale = (g == 0) ? 0.17677669529663689f : 1.0f;
    const float* W = (g == 0) ? Wq : ((g == 1) ? Wk : Wv);
    Bt[n * 256 + kk] = __float2bfloat16(W[kk * 256 + c] * scale);
    if (kk == 0) {
      const float* bb = (g == 0) ? bq : ((g == 1) ? bk : bv);
      biasP[n] = bb[c] * scale;
    }
    return;
  }
  b -= 768;
  if (b < 196) {                       // ---- row_ptr ----
    int i = b * 256 + threadIdx.x;
    if (i > kN) return;
    int lo = 0, hi = kE;
    while (lo < hi) {
      int mid = (lo + hi) >> 1;
      if (er[mid] < i) lo = mid + 1; else hi = mid;
    }
    rp[i] = lo;
    return;
  }
  b -= 196;
  {                                    // ---- cv pack ----
    const int e4 = (b * 256 + threadIdx.x) * 4;
    if (e4 < kE) {
      i32x4 c = *(const i32x4*)(ci + e4);
      f32x4 w = *(const f32x4*)(vl + e4);
      i32x4 o0 = {c[0], __float_as_int(w[0]), c[1], __float_as_int(w[1])};
      i32x4 o1 = {c[2], __float_as_int(w[2]), c[3], __float_as_int(w[3])};
      *(i32x4*)(cv + e4)     = o0;
      *(i32x4*)(cv + e4 + 2) = o1;
    }
  }
}

// ---------------------------------------------------------------------------
// Fused MFMA GEMM (v8): C[50000][768] = A * Bt^T + bias.
// 64 KB LDS double-buffer, prefetch next K-tile before computing current,
// one barrier per K-step. XCD-aware decode; LDS-staged coalesced epilogue.
// ---------------------------------------------------------------------------
__global__ __launch_bounds__(256) void gemm_qkv_kernel(
    const __hip_bfloat16* __restrict__ Ah,
    const __hip_bfloat16* __restrict__ Bt, const float* __restrict__ biasP,
    __hip_bfloat16* __restrict__ qb, __hip_bfloat16* __restrict__ kvb) {
  __shared__ __align__(16) char smemRaw[65536];   // A0|B0|A1|B1 x 16 KB
  short* smemC = (short*)smemRaw;                 // [128][136] C tile (epilogue)

  // XCD-aware decode: L = xcd + 8*(n + 6*mg), m-tile = mg*8 + xcd
  const int L   = blockIdx.x;
  const int xcd = L & 7;
  const int t_  = L >> 3;
  const int nt  = t_ % 6;
  const int mg  = t_ / 6;
  const int mt  = mg * 8 + xcd;
  if (mt >= 391) return;
  const int colBase = nt * 128;
  const int rowBase = mt * 128;

  const int tid  = threadIdx.x;
  const int wave = tid >> 6;
  const int lane = tid & 63;
  const int wm = wave & 1;            // M half of tile
  const int wn = wave >> 1;           // N half

  f32x4 acc[4][4];
#pragma unroll
  for (int i = 0; i < 4; ++i)
#pragma unroll
    for (int j = 0; j < 4; ++j) acc[i][j] = f32x4{0.f, 0.f, 0.f, 0.f};

  // stage A+B tiles for K-step base K0 into buffer BUF (async, no wait)
#define STAGE(BUF, K0)                                                      \
  {                                                                         \
    char* dA = smemRaw + (BUF) * 32768;                                     \
    char* dB = dA + 16384;                                                  \
    _Pragma("unroll")                                                       \
    for (int j = 0; j < 4; ++j) {                                           \
      int s = (wave * 4 + j) * 64 + lane;                                   \
      int r = s >> 3, cp = s & 7;                                           \
      int c = cp ^ (r & 7);                                                 \
      int grow = rowBase + r;                                               \
      grow = grow < kN ? grow : kN - 1;                                     \
      load_lds16((const char*)Ah + (size_t)grow * 512 + (K0) * 2 + c * 16,  \
                 dA + (wave * 4 + j) * 1024);                               \
      load_lds16((const char*)Bt + (size_t)(colBase + r) * 512 + (K0) * 2 + c * 16, \
                 dB + (wave * 4 + j) * 1024);                               \
    }                                                                       \
  }

  STAGE(0, 0);
  __syncthreads();                     // tile 0 resident

  const int rq = lane & 15, qd = lane >> 4;
#pragma unroll
  for (int t = 0; t < 4; ++t) {
    if (t < 3) STAGE((t + 1) & 1, (t + 1) * 64);   // prefetch next tile
    const short* sA = (const short*)(smemRaw + (t & 1) * 32768);
    const short* sB = sA + 8192;                    // +16384 bytes
#pragma unroll
    for (int ks = 0; ks < 2; ++ks) {
      bf16x8 af[4], bfr[4];
#pragma unroll
      for (int mi = 0; mi < 4; ++mi) {
        int r = wm * 64 + mi * 16 + rq;
        int c = (ks * 4 + qd) ^ (r & 7);
        af[mi] = *(const bf16x8*)&sA[r * 64 + c * 8];
      }
#pragma unroll
      for (int nj = 0; nj < 4; ++nj) {
        int r = wn * 64 + nj * 16 + rq;
        int c = (ks * 4 + qd) ^ (r & 7);
        bfr[nj] = *(const bf16x8*)&sB[r * 64 + c * 8];
      }
#pragma unroll
      for (int mi = 0; mi < 4; ++mi)
#pragma unroll
        for (int nj = 0; nj < 4; ++nj)
          acc[mi][nj] = __builtin_amdgcn_mfma_f32_16x16x32_bf16(
              af[mi], bfr[nj], acc[mi][nj], 0, 0, 0);
    }
    __syncthreads();   // drains prefetch (vmcnt) AFTER compute; next tile ready
  }
#undef STAGE

  // ---- epilogue: stage bf16 C tile in LDS, then coalesced stores.
  // C frag layout: row=(lane>>4)*4+reg, col=lane&15 (verified m89/m91).
#pragma unroll
  for (int nj = 0; nj < 4; ++nj) {
    const int cl = wn * 64 + nj * 16 + (lane & 15);
    const float bb = biasP[colBase + cl];
#pragma unroll
    for (int mi = 0; mi < 4; ++mi) {
      const int rl = wm * 64 + mi * 16 + (lane >> 4) * 4;
#pragma unroll
      for (int reg = 0; reg < 4; ++reg) {
        smemC[(rl + reg) * 136 + cl] = (short)f2bu(acc[mi][nj][reg] + bb);
      }
    }
  }
  __syncthreads();

  const int g = colBase >> 8;   // block-uniform: 0=q 1=k 2=v
#pragma unroll
  for (int it = 0; it < 8; ++it) {
    const int r   = it * 16 + (tid >> 4);      // 0..127
    const int c16 = tid & 15;                  // 16B chunk within row
    const int row = rowBase + r;
    if (row < kN) {
      bf16x8 vls = *(const bf16x8*)&smemC[r * 136 + c16 * 8];
      const int cc = (colBase & 255) + c16 * 8;
      __hip_bfloat16* dst =
          (g == 0) ? (qb + (size_t)row * 256 + cc)
                   : (kvb + (size_t)row * 512 + (g == 2 ? 256 : 0) + cc);
      *(bf16x8*)dst = vls;
    }
  }
}

// ---------------------------------------------------------------------------
// Fused SDDMM + segment softmax + SpMM — exact v6 (session best: 114.2 us,
// VGPR 60, occupancy 40%, BW 3.94 TB/s). One row per wave, 128-thread
// blocks, stride-8 tail granularity, packed (col,val) dwordx2, f32x2 packed
// math, col/val 2-3 groups ahead in ping-pong banks, k/v one group ahead,
// DPP quad reduction, log2(e) folded into q (p = exp2(s)).
//
// Session ledger (8 variants, all 114-119 us, BW pinned 3.8-3.9 TB/s):
// deeper pipelines / more rows per wave / refill guards all trade VGPR ->
// occupancy and net zero — Little's-law signature of a saturated random-
// gather service path. This config is the measured optimum of that trade.
// ---------------------------------------------------------------------------
__global__ __launch_bounds__(128) void edge_attn_kernel(
    const __hip_bfloat16* __restrict__ qb, const __hip_bfloat16* __restrict__ kvb,
    const int* __restrict__ row_ptr, const i32x2* __restrict__ cvp,
    float* __restrict__ out) {
  const int wave = threadIdx.x >> 6;
  const int lane = threadIdx.x & 63;
  const int half = lane >> 5;        // which edge of the pair
  const int sl   = lane & 31;        // channel-group lane (8 ch each)
  const int row = blockIdx.x * 2 + wave;
  if (row >= kN) return;

  const int e0 = row_ptr[row];
  const int e1 = row_ptr[row + 1];

  // q channels sl*8 .. sl*8+7, pre-scaled by log2(e) so p = exp2(s)
  const us8 qu = *(const us8*)(qb + (size_t)row * 256 + sl * 8);
  f32x2 qf2[4];
#pragma unroll
  for (int j = 0; j < 4; ++j)
    qf2[j] = f32x2{b2f(qu[2 * j]) * 1.4426950408889634f,
                   b2f(qu[2 * j + 1]) * 1.4426950408889634f};

  float denom = 0.f;
  f32x2 acc2[4];
#pragma unroll
  for (int j = 0; j < 4; ++j) acc2[j] = f32x2{0.f, 0.f};

  if (e0 < e1) {
    const char* kvbL = (const char*)kvb + sl * 16;
    const int elast = e1 - 1;

    u32x4 kS[4], vS[4];        // k/v data for the CURRENT group's 8 edges
    float wS[4];               // val for the current group's 8 edges
    i32x2 cvA[4], cvB[4];      // (col,val) for groups +1 / +2 (ping-pong)

    // ---- warmup ----
    i32x2 c0[4];
#pragma unroll
    for (int j = 0; j < 4; ++j) {        // group 0 cols
      const int ea = min(e0 + 2 * j + half, elast);
      c0[j] = cvp[ea];
    }
#pragma unroll
    for (int j = 0; j < 4; ++j) {        // group 1 cols
      const int eb = min(e0 + 8 + 2 * j + half, elast);
      cvA[j] = cvp[eb];
    }
#pragma unroll
    for (int j = 0; j < 4; ++j) {        // group 2 cols (in flight thru group 0)
      const int ec = min(e0 + 16 + 2 * j + half, elast);
      cvB[j] = cvp[ec];
    }
#pragma unroll
    for (int j = 0; j < 4; ++j) {        // group 0 k/v gathers
      const size_t off = (size_t)c0[j][0] * 1024;
      kS[j] = *(const u32x4*)(kvbL + off);
      vS[j] = *(const u32x4*)(kvbL + off + 512);
      wS[j] = __int_as_float(c0[j][1]);
    }

    // GROUP(EB, CB): consumes edges [EB, EB+8); refills k/v for [EB+8, EB+16)
    // from bank CB (resident); loads (col,val) for [EB+24, EB+32) back into CB.
#define ATTN_GROUP(EB, CB)                                                \
    _Pragma("unroll")                                                     \
    for (int j = 0; j < 4; ++j) {                                         \
      const u32x4 kc = kS[j], vc = vS[j];                                 \
      const float wc = wS[j];                                             \
      {                                                                   \
        const size_t off = (size_t)CB[j][0] * 1024;                       \
        kS[j] = *(const u32x4*)(kvbL + off);                              \
        vS[j] = *(const u32x4*)(kvbL + off + 512);                        \
        wS[j] = __int_as_float(CB[j][1]);                                 \
      }                                                                   \
      {                                                                   \
        const int en = min((EB) + 24 + 2 * j + half, elast);              \
        CB[j] = cvp[en];                                                  \
      }                                                                   \
      f32x2 s2 = qf2[0] * bf2up(kc[0]);                                   \
      s2 += qf2[1] * bf2up(kc[1]);                                        \
      s2 += qf2[2] * bf2up(kc[2]);                                        \
      s2 += qf2[3] * bf2up(kc[3]);                                        \
      float s = s2[0] + s2[1];                                            \
      s = quad_add_xor1(s);                                               \
      s = quad_add_xor2(s);        /* 4-lane head group reduced */        \
      s *= wc;                                                            \
      float p = exp2f(s);                                                 \
      p = (((EB) + 2 * j + half) < e1) ? p : 0.f;                         \
      denom += p;                                                         \
      const f32x2 p2 = {p, p};                                            \
      acc2[0] += p2 * bf2up(vc[0]);                                       \
      acc2[1] += p2 * bf2up(vc[1]);                                       \
      acc2[2] += p2 * bf2up(vc[2]);                                       \
      acc2[3] += p2 * bf2up(vc[3]);                                       \
    }

    // stride-8 loop: exit check BETWEEN groups; banks statically indexed.
    int e = e0;
    for (;;) {
      ATTN_GROUP(e, cvA);
      e += 8; if (e >= e1) break;
      ATTN_GROUP(e, cvB);
      e += 8; if (e >= e1) break;
    }
#undef ATTN_GROUP
  }

  // combine the two halves
  float accs[8];
#pragma unroll
  for (int j = 0; j < 8; ++j) {
    float a = (j & 1) ? acc2[j >> 1][1] : acc2[j >> 1][0];
    accs[j] = a + __shfl_xor(a, 32);
  }
  denom += __shfl_xor(denom, 32);

  const float inv = (denom > 0.f) ? (1.0f / denom) : 0.f;
  // lane's channels cc = sl*8 + j live in head h = sl>>2, dim d=(sl&3)*8+j.
  // This lane writes j = half*4 .. half*4+3; ref channel c = d*8 + h.
  const int h = sl >> 2;
  const int dbase = (sl & 3) * 8 + half * 4;
  float* o = out + (size_t)row * 256 + h;
#pragma unroll
  for (int jj = 0; jj < 4; ++jj)
    o[(dbase + jj) * 8] = accs[half * 4 + jj] * inv;
}

// ---------------------------------------------------------------------------
extern "C" void kernel_launch(void* const* d_in, const int* in_sizes, int n_in,
                              void* d_out, int out_size, void* d_ws, size_t ws_size,
                              hipStream_t stream) {
  const float* h   = (const float*)d_in[0];
  const float* val = (const float*)d_in[1];
  const float* Wq  = (const float*)d_in[2];
  const float* bq  = (const float*)d_in[3];
  const float* Wk  = (const float*)d_in[4];
  const float* bk  = (const float*)d_in[5];
  const float* Wv  = (const float*)d_in[6];
  const float* bv  = (const float*)d_in[7];
  const int* edge_rows = (const int*)d_in[8];
  const int* col_ind   = (const int*)d_in[9];
  float* out = (float*)d_out;

  char* ws = (char*)d_ws;
  __hip_bfloat16* Ah  = (__hip_bfloat16*)ws;                 ws += (size_t)kN * 256 * 2;
  __hip_bfloat16* Bt  = (__hip_bfloat16*)ws;                 ws += (size_t)768 * 256 * 2;
  float*          biasP = (float*)ws;                        ws += 768 * 4;
  __hip_bfloat16* qb  = (__hip_bfloat16*)ws;                 ws += (size_t)kN * 256 * 2;
  __hip_bfloat16* kvb = (__hip_bfloat16*)ws;                 ws += (size_t)kN * 512 * 2;
  int* row_ptr = (int*)ws;                                   ws += ((size_t)(kN + 1) * 4 + 127) & ~127ull;
  i32x2* cv = (i32x2*)ws;

  // merged prep: split_h + build_bt + row_ptr + cv pack in ONE launch
  prep_all_kernel<<<6250 + 768 + 196 + 782, 256, 0, stream>>>(
      h, Ah, Wq, bq, Wk, bk, Wv, bv, Bt, biasP,
      edge_rows, row_ptr, col_ind, val, cv);

  // 391 M-tiles padded to 49 groups of 8; 6 N-tiles; 8 XCD slots
  gemm_qkv_kernel<<<8 * 6 * 49, 256, 0, stream>>>(Ah, Bt, biasP, qb, kvb);

  edge_attn_kernel<<<(kN + 1) / 2, 128, 0, stream>>>(qb, kvb, row_ptr, cv, out);
}